// Round 3
// baseline (185.497 us; speedup 1.0000x reference)
//
#include <hip/hip_runtime.h>

// Problem constants (setup_inputs: B=256, T=16, H=W=160, sms=2 -> t=16, h=w=80)
#define T_DIM 16
#define H2 80
#define W2 80
#define SLICE (H2 * W2)          // 6400 floats per t-slice
#define SAMPLE (T_DIM * SLICE)   // 102400 floats per sample
#define BANDS 5                  // row-bands per sample
#define ROWS_PER_BAND (H2 / BANDS)  // 16 rows
#define FCOLS (W2 / 4)              // 20 float4 columns per row
#define BLOCK (ROWS_PER_BAND * FCOLS)  // 320 threads, one float4 each per slice

__device__ __forceinline__ float4 relu4(float4 v) {
    v.x = fmaxf(v.x, 0.f); v.y = fmaxf(v.y, 0.f);
    v.z = fmaxf(v.z, 0.f); v.w = fmaxf(v.w, 0.f);
    return v;
}

// Phase 1: per-sample linear sums (S0, Sx, Sy, Sq) + TV sums (h, w, t).
// ROW-MAJOR lane map (coalesced own-loads: 8 contiguous 128B lines per wave)
// + SHUFFLE neighbors:
//   - h-neighbor (r+1, cx) == tid+20 -> __shfl_down(v, 20), valid lanes 0..43;
//     lanes 44..63 (20/64) fall back to a global float4 load (clamped at y==79).
//   - w-neighbor (r, cx+1).x == tid+1 -> __shfl_down(v.x, 1); fallback only at
//     lane==63 with cx<19 (<=1 lane/wave); cx==19 row-end needs no value at all
//     (diff is 0 -> use v.w).
// L1 traffic per wave-iter: 1024B own + 320B h-fallback + ~4B w = 1348B
// vs 2304B for the full-reload variant. Still BARRIER-FREE: no __syncthreads
// in the hot loop -> no vmcnt(0) drain, loads pipeline across iterations.
// t-diffs stay register-resident via prev.
__global__ __launch_bounds__(BLOCK) void tsr_phase1(const float* __restrict__ scores,
                                                    float* __restrict__ ws) {
    __shared__ float red[(BLOCK / 64) * 7];

    const int blk  = blockIdx.x;
    const int b    = blk / BANDS;
    const int band = blk % BANDS;
    const int tid  = threadIdx.x;
    const int lane = tid & 63;

    const int r   = tid / FCOLS;      // local row 0..15
    const int cx  = tid % FCOLS;      // float4 index within row, 0..19
    const int y0  = band * ROWS_PER_BAND;
    const int y   = y0 + r;
    const int xb  = cx * 4;

    const float step = 2.0f / (float)(H2 - 1);   // h == w == 80 -> same step
    const float yy  = -1.0f + (float)y * step;
    const float xx0 = -1.0f + (float)(xb + 0) * step;
    const float xx1 = -1.0f + (float)(xb + 1) * step;
    const float xx2 = -1.0f + (float)(xb + 2) * step;
    const float xx3 = -1.0f + (float)(xb + 3) * step;
    const float yy2 = yy * yy;
    const float cq0 = xx0 * xx0 + yy2;
    const float cq1 = xx1 * xx1 + yy2;
    const float cq2 = xx2 * xx2 + yy2;
    const float cq3 = xx3 * xx3 + yy2;

    const float* sampBase = scores + (size_t)b * SAMPLE;
    const int rowOff = y * W2 + xb;                          // own float4 (floats)
    const int hOff   = (y + 1 < H2) ? rowOff + W2 : rowOff;  // clamped -> diff 0
    // loop-invariant predicates (compiler hoists the v_cmp; loads are
    // exec-masked in-line, no branches in the hot loop)
    const bool hFall = (lane >= 44);                 // tid+20 crosses wave
    const bool wEnd  = (cx == FCOLS - 1);            // row end: boundary diff = 0
    const bool wFall = (lane == 63) && !wEnd;        // tid+1 crosses wave

    float s0 = 0.f, sx = 0.f, sy = 0.f, sq = 0.f;
    float tvh = 0.f, tvw = 0.f, tvt = 0.f;
    float4 prev = make_float4(0.f, 0.f, 0.f, 0.f);

#pragma unroll 4
    for (int t = 0; t < T_DIM; ++t) {
        const float* sl = sampBase + (size_t)t * SLICE;
        const float4 v = relu4(*(const float4*)(sl + rowOff));

        // h-neighbor (already relu'd for shuffle lanes)
        float4 hN;
        hN.x = __shfl_down(v.x, 20);
        hN.y = __shfl_down(v.y, 20);
        hN.z = __shfl_down(v.z, 20);
        hN.w = __shfl_down(v.w, 20);
        // w-neighbor scalar
        float wN = __shfl_down(v.x, 1);
        if (hFall) hN = relu4(*(const float4*)(sl + hOff));    // 20 lanes/wave
        if (wFall) wN = fmaxf(sl[rowOff + 4], 0.f);            // <=1 lane/wave
        if (wEnd)  wN = v.w;                                   // diff -> 0

        // linear sums
        const float rs = v.x + v.y + v.z + v.w;
        s0 += rs;
        sy = fmaf(yy, rs, sy);
        sx = fmaf(xx0, v.x, sx); sx = fmaf(xx1, v.y, sx);
        sx = fmaf(xx2, v.z, sx); sx = fmaf(xx3, v.w, sx);
        sq = fmaf(cq0, v.x, sq); sq = fmaf(cq1, v.y, sq);
        sq = fmaf(cq2, v.z, sq); sq = fmaf(cq3, v.w, sq);

        // w-diffs: 3 internal + boundary (0 at row end)
        tvw += fabsf(v.y - v.x) + fabsf(v.z - v.y) + fabsf(v.w - v.z)
             + fabsf(wN - v.w);

        // h-diffs vs next row (clamped -> 0 at y==79)
        tvh += fabsf(hN.x - v.x) + fabsf(hN.y - v.y) +
               fabsf(hN.z - v.z) + fabsf(hN.w - v.w);

        // t-diffs: register-resident
        if (t > 0) {
            tvt += fabsf(v.x - prev.x) + fabsf(v.y - prev.y) +
                   fabsf(v.z - prev.z) + fabsf(v.w - prev.w);
        }
        prev = v;
    }

    // block reduction: wave shuffle, then cross-wave via LDS
    float acc[7] = {s0, sx, sy, sq, tvh, tvw, tvt};
#pragma unroll
    for (int off = 32; off > 0; off >>= 1) {
#pragma unroll
        for (int i = 0; i < 7; ++i) acc[i] += __shfl_down(acc[i], off);
    }
    const int wave = tid >> 6;
    if (lane == 0) {
#pragma unroll
        for (int i = 0; i < 7; ++i) red[wave * 7 + i] = acc[i];
    }
    __syncthreads();
    if (tid < 7) {
        float s = 0.f;
#pragma unroll
        for (int wv = 0; wv < BLOCK / 64; ++wv) s += red[wv * 7 + tid];
        ws[blk * 8 + tid] = s;  // distinct slot per block -> no init, no atomics
    }
}

// Phase 2: sum band partials per sample, nonlinear combine, batch mean -> scalar
__global__ __launch_bounds__(256) void tsr_finalize(const float* __restrict__ ws,
                                                    float* __restrict__ out, int B) {
    __shared__ float red[256];
    const int tid = threadIdx.x;
    float acc = 0.f;
    const float ch = 1.0f / (float)(T_DIM * (H2 - 1) * W2);       // 1/101120
    const float cw = 1.0f / (float)(T_DIM * H2 * (W2 - 1));       // 1/101120
    const float ct = 0.3f / (float)((T_DIM - 1) * H2 * W2);       // 0.3/96000
    for (int b = tid; b < B; b += 256) {
        float p[7] = {0.f, 0.f, 0.f, 0.f, 0.f, 0.f, 0.f};
        for (int band = 0; band < BANDS; ++band) {
            const float* w = ws + (size_t)(b * BANDS + band) * 8;
#pragma unroll
            for (int i = 0; i < 7; ++i) p[i] += w[i];
        }
        const float S0 = p[0], Sx = p[1], Sy = p[2], Sq = p[3];
        const float Th = p[4], Tw = p[5], Tt = p[6];
        const float tot = fmaxf(S0, 1e-6f);
        const float inv = 1.0f / tot;
        const float mux = Sx * inv, muy = Sy * inv;
        const float m2 = mux * mux + muy * muy;
        const float compact = Sq * inv - 2.0f * m2 + m2 * (S0 * inv);
        const float tv = Th * ch + Tw * cw + Tt * ct;
        acc += compact + tv;
    }
    red[tid] = acc;
    __syncthreads();
    for (int s = 128; s > 0; s >>= 1) {
        if (tid < s) red[tid] += red[tid + s];
        __syncthreads();
    }
    if (tid == 0) out[0] = red[0] / (float)B;
}

extern "C" void kernel_launch(void* const* d_in, const int* in_sizes, int n_in,
                              void* d_out, int out_size, void* d_ws, size_t ws_size,
                              hipStream_t stream) {
    const float* scores = (const float*)d_in[0];
    const int B = in_sizes[0] / SAMPLE;  // 256
    float* ws = (float*)d_ws;

    tsr_phase1<<<B * BANDS, BLOCK, 0, stream>>>(scores, ws);
    tsr_finalize<<<1, 256, 0, stream>>>(ws, (float*)d_out, B);
}

// Round 4
// 166.417 us; speedup vs baseline: 1.1147x; 1.1147x over previous
//
#include <hip/hip_runtime.h>

// Problem constants (setup_inputs: B=256, T=16, H=W=160, sms=2 -> t=16, h=w=80)
#define T_DIM 16
#define H2 80
#define W2 80
#define SLICE (H2 * W2)          // 6400 floats per t-slice
#define SAMPLE (T_DIM * SLICE)   // 102400 floats per sample
#define TSPLIT 4                 // t-quarters per sample
#define TCHUNK (T_DIM / TSPLIT)  // 4 slices per block
#define RSTRIP 5                 // rows per thread (vertical register strip)
#define NSTRIP (H2 / RSTRIP)     // 16 strips cover all 80 rows
#define BLOCK (NSTRIP * (W2 / 4))  // 16 * 20 = 320 threads

__device__ __forceinline__ float4 relu4(float4 v) {
    v.x = fmaxf(v.x, 0.f); v.y = fmaxf(v.y, 0.f);
    v.z = fmaxf(v.z, 0.f); v.w = fmaxf(v.w, 0.f);
    return v;
}

// Phase 1, VERTICAL-STRIP version. Thread owns 5 consecutive rows at one
// float4 column. Consequences (vs 1-row/thread round-0 structure):
//   - t-diffs: register-resident (prev[5])                      [was: registers]
//   - h-diffs: 4/5 register-local (v[k+1]-v[k]); only the strip-bottom
//     neighbor row is loaded (L1 hit: it is another lane's own row)
//   - w-diffs: 3 internal + 1 boundary scalar per row (same-line L1 hit)
// NO cross-lane ops (r1/r3 showed 5 bpermutes/iter cost +26us regardless of
// coalescing), NO barriers in the hot loop. 11 independent loads + ~200 VALU
// per thread-iter -> 5x the independent work per dependency chain; wave-iter
// count drops 4.2x. Own-loads stay dense: 20 lanes per row = contiguous 320B.
// Grid = 256 samples x 4 t-quarters; quarter h>0 reloads slice 4h-1 to seed
// prev (h==0 seeds from its own first slice -> t-diff contributes 0 at t=0).
__global__ __launch_bounds__(BLOCK) void tsr_phase1(const float* __restrict__ scores,
                                                    float* __restrict__ ws) {
    __shared__ float red[(BLOCK / 64) * 7];

    const int blk  = blockIdx.x;
    const int b    = blk >> 2;       // sample
    const int h    = blk & 3;        // t-quarter
    const int tid  = threadIdx.x;
    const int lane = tid & 63;

    const int strip   = tid / 20;        // 0..15
    const int cx      = tid % 20;        // 0..19
    const int rowBase = strip * RSTRIP;  // 0,5,...,75
    const int xb      = cx * 4;

    const float step = 2.0f / (float)(H2 - 1);
    const float xx0 = -1.0f + (float)xb * step;
    const float xx1 = xx0 + step, xx2 = xx1 + step, xx3 = xx2 + step;
    float yyv[RSTRIP], yy2v[RSTRIP];
#pragma unroll
    for (int k = 0; k < RSTRIP; ++k) {
        yyv[k]  = -1.0f + (float)(rowBase + k) * step;
        yy2v[k] = yyv[k] * yyv[k];
    }

    // Per-thread base offsets (floats). Row k folds into the load's imm
    // offset (k*W2*4B = 320B*k <= 4KB), so only these 3 bases live in regs.
    const int off0   = rowBase * W2 + xb;                 // own strip top
    const int wdelta = (cx < 19) ? 4 : 3;                 // cx==19: own .w -> diff 0
    const int hrow   = (rowBase + RSTRIP < H2) ? rowBase + RSTRIP : H2 - 1;
    const int hoff   = hrow * W2 + xb;                    // clamp -> diff 0 at strip 15

    const float* samp = scores + (size_t)b * SAMPLE;
    const float* tb   = samp + (size_t)(h * TCHUNK) * SLICE;

    // accumulators: column sums (serve s0, sx, sq-x at fold time), y-moments,
    // and the three TV sums
    float cs0 = 0.f, cs1 = 0.f, cs2 = 0.f, cs3 = 0.f;
    float sy = 0.f, sqy = 0.f, tvh = 0.f, tvw = 0.f, tvt = 0.f;

    // seed prev: quarter h>0 from slice 4h-1 (not accumulated); h==0 from
    // slice 0 (self -> first t-diff is exactly 0, matching "no pair at t=0")
    float4 prev[RSTRIP];
    {
        const float* sl = (h > 0) ? (tb - SLICE) : tb;
        const float* base = sl + off0;
#pragma unroll
        for (int k = 0; k < RSTRIP; ++k)
            prev[k] = relu4(*(const float4*)(base + k * W2));
    }

#pragma unroll
    for (int i = 0; i < TCHUNK; ++i) {
        const float* sl    = tb + (size_t)i * SLICE;
        const float* base  = sl + off0;
        const float* wbase = base + wdelta;
        const float* hbase = sl + hoff;

        float4 v[RSTRIP];
        float  wn[RSTRIP];
#pragma unroll
        for (int k = 0; k < RSTRIP; ++k)
            v[k] = relu4(*(const float4*)(base + k * W2));
        const float4 hn = relu4(*(const float4*)hbase);
#pragma unroll
        for (int k = 0; k < RSTRIP; ++k)
            wn[k] = fmaxf(wbase[k * W2], 0.f);

#pragma unroll
        for (int k = 0; k < RSTRIP; ++k) {
            const float4 vk = v[k];
            cs0 += vk.x; cs1 += vk.y; cs2 += vk.z; cs3 += vk.w;
            const float rs = (vk.x + vk.y) + (vk.z + vk.w);
            sy  = fmaf(yyv[k],  rs, sy);
            sqy = fmaf(yy2v[k], rs, sqy);
            // w-diffs: 3 internal + boundary (0 at row end via wdelta clamp)
            tvw += fabsf(vk.y - vk.x) + fabsf(vk.z - vk.y) +
                   fabsf(vk.w - vk.z) + fabsf(wn[k] - vk.w);
            // h-diffs: next own row for k<4, loaded neighbor row for k==4
            const float4 nk = (k < RSTRIP - 1) ? v[k + 1] : hn;
            tvh += fabsf(nk.x - vk.x) + fabsf(nk.y - vk.y) +
                   fabsf(nk.z - vk.z) + fabsf(nk.w - vk.w);
            // t-diffs: register-resident (i==0,h==0: v==prev -> 0)
            tvt += fabsf(vk.x - prev[k].x) + fabsf(vk.y - prev[k].y) +
                   fabsf(vk.z - prev[k].z) + fabsf(vk.w - prev[k].w);
        }
#pragma unroll
        for (int k = 0; k < RSTRIP; ++k) prev[k] = v[k];
    }

    // fold column sums into the linear moments
    const float s0 = (cs0 + cs1) + (cs2 + cs3);
    const float sx = ((xx0 * cs0 + xx1 * cs1) + (xx2 * cs2 + xx3 * cs3));
    float sq = sqy;
    sq = fmaf(xx0 * xx0, cs0, sq); sq = fmaf(xx1 * xx1, cs1, sq);
    sq = fmaf(xx2 * xx2, cs2, sq); sq = fmaf(xx3 * xx3, cs3, sq);

    // block reduction: wave shuffle, then cross-wave via LDS
    float acc[7] = {s0, sx, sy, sq, tvh, tvw, tvt};
#pragma unroll
    for (int off = 32; off > 0; off >>= 1) {
#pragma unroll
        for (int i = 0; i < 7; ++i) acc[i] += __shfl_down(acc[i], off);
    }
    const int wave = tid >> 6;
    if (lane == 0) {
#pragma unroll
        for (int i = 0; i < 7; ++i) red[wave * 7 + i] = acc[i];
    }
    __syncthreads();
    if (tid < 7) {
        float s = 0.f;
#pragma unroll
        for (int wv = 0; wv < BLOCK / 64; ++wv) s += red[wv * 7 + tid];
        ws[blk * 8 + tid] = s;  // distinct slot per block -> no init, no atomics
    }
}

// Phase 2: sum the 4 t-quarter partials per sample, nonlinear combine,
// batch mean -> scalar
__global__ __launch_bounds__(256) void tsr_finalize(const float* __restrict__ ws,
                                                    float* __restrict__ out, int B) {
    __shared__ float red[256];
    const int tid = threadIdx.x;
    float acc = 0.f;
    const float ch = 1.0f / (float)(T_DIM * (H2 - 1) * W2);       // 1/101120
    const float cw = 1.0f / (float)(T_DIM * H2 * (W2 - 1));       // 1/101120
    const float ct = 0.3f / (float)((T_DIM - 1) * H2 * W2);       // 0.3/96000
    for (int b = tid; b < B; b += 256) {
        float p[7] = {0.f, 0.f, 0.f, 0.f, 0.f, 0.f, 0.f};
        for (int part = 0; part < TSPLIT; ++part) {
            const float* w = ws + (size_t)(b * TSPLIT + part) * 8;
#pragma unroll
            for (int i = 0; i < 7; ++i) p[i] += w[i];
        }
        const float S0 = p[0], Sx = p[1], Sy = p[2], Sq = p[3];
        const float Th = p[4], Tw = p[5], Tt = p[6];
        const float tot = fmaxf(S0, 1e-6f);
        const float inv = 1.0f / tot;
        const float mux = Sx * inv, muy = Sy * inv;
        const float m2 = mux * mux + muy * muy;
        const float compact = Sq * inv - 2.0f * m2 + m2 * (S0 * inv);
        const float tv = Th * ch + Tw * cw + Tt * ct;
        acc += compact + tv;
    }
    red[tid] = acc;
    __syncthreads();
    for (int s = 128; s > 0; s >>= 1) {
        if (tid < s) red[tid] += red[tid + s];
        __syncthreads();
    }
    if (tid == 0) out[0] = red[0] / (float)B;
}

extern "C" void kernel_launch(void* const* d_in, const int* in_sizes, int n_in,
                              void* d_out, int out_size, void* d_ws, size_t ws_size,
                              hipStream_t stream) {
    const float* scores = (const float*)d_in[0];
    const int B = in_sizes[0] / SAMPLE;  // 256
    float* ws = (float*)d_ws;

    tsr_phase1<<<B * TSPLIT, BLOCK, 0, stream>>>(scores, ws);
    tsr_finalize<<<1, 256, 0, stream>>>(ws, (float*)d_out, B);
}